// Round 1
// baseline (751.186 us; speedup 1.0000x reference)
//
#include <hip/hip_runtime.h>
#include <cstddef>
#include <cstdint>

// ---------------------------------------------------------------------------
// Shapes (fixed by the reference):
//  heatmap  (16, 64, 256, 256)  f32
//  pos_embed(16, 32, 256, 256)  f32
//  feat1    (16, 96, 128, 128)  f32
//  feat2    (16,384,  64,  64)  f32
//  feat3    (16,512,  32,  32)  f32
//  W1 (992,1024) b1(1024) ; W2(1024,512) ; W3(512,256) ; W4(256,224)
//  out (16, 256, 64) f32 : rows 0..223 = MLP output (transposed), 224..255 = positions
// ---------------------------------------------------------------------------

// ---- Kernel 1: per-(b,j) argmax over 256x256 plane ------------------------
__global__ __launch_bounds__(256) void argmax_kernel(const float* __restrict__ hm,
                                                     int* __restrict__ peaks) {
    __shared__ float sval[256];
    __shared__ int   sidx[256];
    const int plane = blockIdx.x;                       // b*64 + j
    const float4* p4 = (const float4*)(hm + (size_t)plane * 65536);
    const int tid = threadIdx.x;
    float best = -3.402823466e38f;
    int bidx = 0;
    // thread covers ascending indices -> strict '>' keeps first occurrence
    for (int i = tid; i < 16384; i += 256) {
        float4 v = p4[i];
        int base = i << 2;
        if (v.x > best) { best = v.x; bidx = base; }
        if (v.y > best) { best = v.y; bidx = base + 1; }
        if (v.z > best) { best = v.z; bidx = base + 2; }
        if (v.w > best) { best = v.w; bidx = base + 3; }
    }
    sval[tid] = best; sidx[tid] = bidx;
    __syncthreads();
    for (int s = 128; s > 0; s >>= 1) {
        if (tid < s) {
            float ov = sval[tid + s]; int oi = sidx[tid + s];
            if (ov > sval[tid] || (ov == sval[tid] && oi < sidx[tid])) {
                sval[tid] = ov; sidx[tid] = oi;
            }
        }
        __syncthreads();
    }
    if (tid == 0) peaks[plane] = sidx[0];
}

// ---- Kernel 2: gather (nearest positions + bilinear features) -------------
__device__ inline void bilinear_block(const float* __restrict__ fb, int C, int H, int W,
                                      float gx, float gy, float* __restrict__ dst, int tid) {
    const float x = (gx + 1.0f) * 0.5f * (float)(W - 1);
    const float y = (gy + 1.0f) * 0.5f * (float)(H - 1);
    const float x0f = floorf(x), y0f = floorf(y);
    const float wx = x - x0f, wy = y - y0f;
    const int x0 = (int)fminf(fmaxf(x0f,        0.f), (float)(W - 1));
    const int x1 = (int)fminf(fmaxf(x0f + 1.f,  0.f), (float)(W - 1));
    const int y0 = (int)fminf(fmaxf(y0f,        0.f), (float)(H - 1));
    const int y1 = (int)fminf(fmaxf(y0f + 1.f,  0.f), (float)(H - 1));
    const float w00 = (1.f - wx) * (1.f - wy);
    const float w01 = wx * (1.f - wy);
    const float w10 = (1.f - wx) * wy;
    const float w11 = wx * wy;
    const int i00 = y0 * W + x0, i01 = y0 * W + x1;
    const int i10 = y1 * W + x0, i11 = y1 * W + x1;
    const size_t HW = (size_t)H * W;
    for (int c = tid; c < C; c += 256) {
        const float* fc = fb + (size_t)c * HW;
        dst[c] = fc[i00] * w00 + fc[i01] * w01 + fc[i10] * w10 + fc[i11] * w11;
    }
}

__global__ __launch_bounds__(256) void gather_kernel(
    const float* __restrict__ pos_embed,
    const float* __restrict__ feat1, const float* __restrict__ feat2,
    const float* __restrict__ feat3,
    const int* __restrict__ peaks,
    float* __restrict__ X0, float* __restrict__ out) {
    const int plane = blockIdx.x;           // b*64 + j
    const int b = plane >> 6, j = plane & 63;
    const int idx = peaks[plane];
    const int py = idx >> 8, px = idx & 255;
    const float gx = ((float)px - 127.5f) / 127.5f;
    const float gy = ((float)py - 127.5f) / 127.5f;
    const int tid = threadIdx.x;

    // positions: nearest sample == exact peak pixel -> out channels 224..255
    if (tid < 32) {
        float v = pos_embed[((size_t)(b * 32 + tid)) * 65536 + idx];
        out[(size_t)b * 16384 + (size_t)(224 + tid) * 64 + j] = v;
    }

    float* xrow = X0 + (size_t)plane * 992;
    bilinear_block(feat1 + (size_t)b *  96 * 128 * 128,  96, 128, 128, gx, gy, xrow,       tid);
    bilinear_block(feat2 + (size_t)b * 384 *  64 *  64, 384,  64,  64, gx, gy, xrow +  96, tid);
    bilinear_block(feat3 + (size_t)b * 512 *  32 *  32, 512,  32,  32, gx, gy, xrow + 480, tid);
}

// ---- Kernels 3-6: f32 tiled GEMM + bias + ReLU ----------------------------
// BM=BN=64, BK=16, 256 threads, 4x4 micro-tile per thread.
template<bool TRANS_OUT, bool GUARD_N>
__global__ __launch_bounds__(256) void gemm_bias_relu(
    const float* __restrict__ A, const float* __restrict__ Wt,
    const float* __restrict__ bias, float* __restrict__ Y,
    int M, int N, int K) {
    __shared__ float As[16][64];
    __shared__ float Bs[16][64];
    const int tid = threadIdx.x;
    const int tx = tid & 15, ty = tid >> 4;
    const int m0 = blockIdx.y * 64, n0 = blockIdx.x * 64;
    float acc[4][4] = {};

    const int am = tid >> 2;           // 0..63 (row within A tile)
    const int ak = (tid & 3) << 2;     // 0,4,8,12 (k offset)

    for (int k0 = 0; k0 < K; k0 += 16) {
        // A tile: float4 per thread (K is a multiple of 16 for all layers)
        float4 av = *(const float4*)(A + (size_t)(m0 + am) * K + (k0 + ak));
        As[ak + 0][am] = av.x; As[ak + 1][am] = av.y;
        As[ak + 2][am] = av.z; As[ak + 3][am] = av.w;
        // B tile: 4 rows of 64, coalesced along n
        #pragma unroll
        for (int i = 0; i < 4; ++i) {
            int e = i * 256 + tid;
            int kk = e >> 6, nn = e & 63;
            float v = 0.f;
            if (!GUARD_N || (n0 + nn) < N)
                v = Wt[(size_t)(k0 + kk) * N + (n0 + nn)];
            Bs[kk][nn] = v;
        }
        __syncthreads();
        #pragma unroll
        for (int k = 0; k < 16; ++k) {
            float4 a  = *(const float4*)&As[k][ty << 2];
            float4 bv = *(const float4*)&Bs[k][tx << 2];
            float aa[4] = {a.x, a.y, a.z, a.w};
            float bb[4] = {bv.x, bv.y, bv.z, bv.w};
            #pragma unroll
            for (int i = 0; i < 4; ++i)
                #pragma unroll
                for (int jj = 0; jj < 4; ++jj)
                    acc[i][jj] += aa[i] * bb[jj];
        }
        __syncthreads();
    }

    #pragma unroll
    for (int jj = 0; jj < 4; ++jj) {
        int n = n0 + (tx << 2) + jj;
        if (GUARD_N && n >= N) continue;
        float bj = bias[n];
        #pragma unroll
        for (int i = 0; i < 4; ++i) {
            int m = m0 + (ty << 2) + i;
            float v = acc[i][jj] + bj;
            v = v > 0.f ? v : 0.f;
            if (TRANS_OUT) {
                // out[b, n, j] where m = b*64 + j ; out stride (16384, 64, 1)
                int bb2 = m >> 6, j = m & 63;
                Y[(size_t)bb2 * 16384 + (size_t)n * 64 + j] = v;
            } else {
                Y[(size_t)m * N + n] = v;
            }
        }
    }
}

extern "C" void kernel_launch(void* const* d_in, const int* in_sizes, int n_in,
                              void* d_out, int out_size, void* d_ws, size_t ws_size,
                              hipStream_t stream) {
    (void)in_sizes; (void)n_in; (void)out_size; (void)ws_size;
    const float* heatmap   = (const float*)d_in[0];
    const float* pos_embed = (const float*)d_in[1];
    const float* feat1     = (const float*)d_in[2];
    const float* feat2     = (const float*)d_in[3];
    const float* feat3     = (const float*)d_in[4];
    const float* W1 = (const float*)d_in[5];  const float* b1 = (const float*)d_in[6];
    const float* W2 = (const float*)d_in[7];  const float* b2 = (const float*)d_in[8];
    const float* W3 = (const float*)d_in[9];  const float* b3 = (const float*)d_in[10];
    const float* W4 = (const float*)d_in[11]; const float* b4 = (const float*)d_in[12];
    float* out = (float*)d_out;

    char* ws = (char*)d_ws;
    int*   peaks = (int*)ws;                              // 1024 ints
    float* X0 = (float*)(ws + 8192);                      // 1024 x 992
    float* X1 = X0 + (size_t)1024 * 992;                  // 1024 x 1024
    float* X2 = X1 + (size_t)1024 * 1024;                 // 1024 x 512
    float* X3 = X2 + (size_t)1024 * 512;                  // 1024 x 256

    argmax_kernel<<<1024, 256, 0, stream>>>(heatmap, peaks);
    gather_kernel<<<1024, 256, 0, stream>>>(pos_embed, feat1, feat2, feat3, peaks, X0, out);
    gemm_bias_relu<false, false><<<dim3(16, 16), 256, 0, stream>>>(X0, W1, b1, X1, 1024, 1024, 992);
    gemm_bias_relu<false, false><<<dim3( 8, 16), 256, 0, stream>>>(X1, W2, b2, X2, 1024,  512, 1024);
    gemm_bias_relu<false, false><<<dim3( 4, 16), 256, 0, stream>>>(X2, W3, b3, X3, 1024,  256,  512);
    gemm_bias_relu<true,  true ><<<dim3( 4, 16), 256, 0, stream>>>(X3, W4, b4, out, 1024,  224,  256);
}

// Round 2
// 604.392 us; speedup vs baseline: 1.2429x; 1.2429x over previous
//
#include <hip/hip_runtime.h>
#include <hip/hip_bf16.h>
#include <cstddef>
#include <cstdint>

// ---------------------------------------------------------------------------
//  heatmap  (16, 64, 256, 256)  f32
//  pos_embed(16, 32, 256, 256)  f32
//  feat1    (16, 96, 128, 128)  f32
//  feat2    (16,384,  64,  64)  f32
//  feat3    (16,512,  32,  32)  f32
//  W1 (992,1024) ; W2(1024,512) ; W3(512,256) ; W4(256,224)  + biases
//  out (16, 256, 64) f32 : ch 0..223 = MLP out (transposed), 224..255 = positions
//
//  Pipeline: argmax -> gather(bf16 X0 + positions) -> Wt cast/transpose ->
//            4x MFMA bf16 GEMMs (wave-per-32x32-tile, LDS-free, reg prefetch)
// ---------------------------------------------------------------------------

typedef __attribute__((ext_vector_type(8))) short bf16x8;   // 8 bf16 = 4 VGPRs
typedef __attribute__((ext_vector_type(4))) float f32x4;

// ---- Kernel 1: per-(b,j) argmax over 256x256 plane ------------------------
__global__ __launch_bounds__(256) void argmax_kernel(const float* __restrict__ hm,
                                                     int* __restrict__ peaks) {
    __shared__ float sval[256];
    __shared__ int   sidx[256];
    const int plane = blockIdx.x;                       // b*64 + j
    const float4* p4 = (const float4*)(hm + (size_t)plane * 65536);
    const int tid = threadIdx.x;
    float best = -3.402823466e38f;
    int bidx = 0;
    for (int i = tid; i < 16384; i += 256) {
        float4 v = p4[i];
        int base = i << 2;
        if (v.x > best) { best = v.x; bidx = base; }
        if (v.y > best) { best = v.y; bidx = base + 1; }
        if (v.z > best) { best = v.z; bidx = base + 2; }
        if (v.w > best) { best = v.w; bidx = base + 3; }
    }
    sval[tid] = best; sidx[tid] = bidx;
    __syncthreads();
    for (int s = 128; s > 0; s >>= 1) {
        if (tid < s) {
            float ov = sval[tid + s]; int oi = sidx[tid + s];
            if (ov > sval[tid] || (ov == sval[tid] && oi < sidx[tid])) {
                sval[tid] = ov; sidx[tid] = oi;
            }
        }
        __syncthreads();
    }
    if (tid == 0) peaks[plane] = sidx[0];
}

// ---- Kernel 2: gather (nearest positions f32 + bilinear features -> bf16) -
__device__ inline void bilinear_block(const float* __restrict__ fb, int C, int H, int W,
                                      float gx, float gy,
                                      __hip_bfloat16* __restrict__ dst, int tid) {
    const float x = (gx + 1.0f) * 0.5f * (float)(W - 1);
    const float y = (gy + 1.0f) * 0.5f * (float)(H - 1);
    const float x0f = floorf(x), y0f = floorf(y);
    const float wx = x - x0f, wy = y - y0f;
    const int x0 = (int)fminf(fmaxf(x0f,       0.f), (float)(W - 1));
    const int x1 = (int)fminf(fmaxf(x0f + 1.f, 0.f), (float)(W - 1));
    const int y0 = (int)fminf(fmaxf(y0f,       0.f), (float)(H - 1));
    const int y1 = (int)fminf(fmaxf(y0f + 1.f, 0.f), (float)(H - 1));
    const float w00 = (1.f - wx) * (1.f - wy);
    const float w01 = wx * (1.f - wy);
    const float w10 = (1.f - wx) * wy;
    const float w11 = wx * wy;
    const int i00 = y0 * W + x0, i01 = y0 * W + x1;
    const int i10 = y1 * W + x0, i11 = y1 * W + x1;
    const size_t HW = (size_t)H * W;
    for (int c = tid; c < C; c += 256) {
        const float* fc = fb + (size_t)c * HW;
        float v = fc[i00] * w00 + fc[i01] * w01 + fc[i10] * w10 + fc[i11] * w11;
        dst[c] = __float2bfloat16(v);
    }
}

__global__ __launch_bounds__(256) void gather_kernel(
    const float* __restrict__ pos_embed,
    const float* __restrict__ feat1, const float* __restrict__ feat2,
    const float* __restrict__ feat3,
    const int* __restrict__ peaks,
    __hip_bfloat16* __restrict__ X0, float* __restrict__ out) {
    const int plane = blockIdx.x;           // b*64 + j
    const int b = plane >> 6, j = plane & 63;
    const int idx = peaks[plane];
    const int py = idx >> 8, px = idx & 255;
    const float gx = ((float)px - 127.5f) / 127.5f;
    const float gy = ((float)py - 127.5f) / 127.5f;
    const int tid = threadIdx.x;

    if (tid < 32) {
        float v = pos_embed[((size_t)(b * 32 + tid)) * 65536 + idx];
        out[(size_t)b * 16384 + (size_t)(224 + tid) * 64 + j] = v;
    }

    __hip_bfloat16* xrow = X0 + (size_t)plane * 992;
    bilinear_block(feat1 + (size_t)b *  96 * 128 * 128,  96, 128, 128, gx, gy, xrow,       tid);
    bilinear_block(feat2 + (size_t)b * 384 *  64 *  64, 384,  64,  64, gx, gy, xrow +  96, tid);
    bilinear_block(feat3 + (size_t)b * 512 *  32 *  32, 512,  32,  32, gx, gy, xrow + 480, tid);
}

// ---- Kernel 3: weight transpose + cast (f32 KxN -> bf16 NxK), LDS-tiled ---
__global__ __launch_bounds__(256) void wcast_kernel(
    const float* __restrict__ W1, const float* __restrict__ W2,
    const float* __restrict__ W3, const float* __restrict__ W4,
    __hip_bfloat16* __restrict__ T1, __hip_bfloat16* __restrict__ T2,
    __hip_bfloat16* __restrict__ T3, __hip_bfloat16* __restrict__ T4) {
    int bid = blockIdx.x;
    const float* W; __hip_bfloat16* T; int K, N;
    if (bid < 992)        { W = W1; T = T1; K = 992;  N = 1024; }
    else if (bid < 1504)  { bid -= 992;  W = W2; T = T2; K = 1024; N = 512; }
    else if (bid < 1632)  { bid -= 1504; W = W3; T = T3; K = 512;  N = 256; }
    else                  { bid -= 1632; W = W4; T = T4; K = 256;  N = 224; }
    const int tilesN = N >> 5;
    const int tk = bid / tilesN, tn = bid - tk * tilesN;
    __shared__ float tile[32][33];
    const int col = threadIdx.x & 31, rowg = threadIdx.x >> 5;   // rowg 0..7
    #pragma unroll
    for (int i = 0; i < 4; ++i) {
        int k = (tk << 5) + rowg + (i << 3);
        tile[rowg + (i << 3)][col] = W[(size_t)k * N + (tn << 5) + col];
    }
    __syncthreads();
    #pragma unroll
    for (int i = 0; i < 4; ++i) {
        int n = (tn << 5) + rowg + (i << 3);
        T[(size_t)n * K + (tk << 5) + col] = __float2bfloat16(tile[col][rowg + (i << 3)]);
    }
}

// ---- Kernels 4-7: MFMA bf16 GEMM, one wave per 32x32 output tile ----------
// A: [M][K] bf16 row-major. Bt: [N][K] bf16 (W transposed). Y=relu(A@W+b).
// A-frag: lane holds A[m0 + (lane&15)][ (lane>>4)*8 + j ], j=0..7 -> 16B load.
// B-frag: lane holds B[k][n0 + (lane&15)] == Bt[n0+(lane&15)][k] -> 16B load.
// C/D:    col = lane&15, row = (lane>>4)*4 + reg   [measured: learn_hip m89/m91]
template<bool LAST>
__global__ __launch_bounds__(64) void mfma_gemm(
    const short* __restrict__ A, const short* __restrict__ Bt,
    const float* __restrict__ bias, void* __restrict__ Yv,
    int N, int K) {
    const int lane = threadIdx.x;
    const int q = lane >> 4, r = lane & 15;
    const int m0 = blockIdx.y << 5;
    const int n0 = blockIdx.x << 5;

    const short* pa0 = A  + (size_t)(m0 + r) * K + (q << 3);
    const short* pa1 = pa0 + (size_t)16 * K;
    const short* pb0 = Bt + (size_t)(n0 + r) * K + (q << 3);
    const short* pb1 = pb0 + (size_t)16 * K;

    f32x4 acc00 = {0.f,0.f,0.f,0.f}, acc01 = {0.f,0.f,0.f,0.f};
    f32x4 acc10 = {0.f,0.f,0.f,0.f}, acc11 = {0.f,0.f,0.f,0.f};

    bf16x8 a0 = *(const bf16x8*)pa0;
    bf16x8 a1 = *(const bf16x8*)pa1;
    bf16x8 b0 = *(const bf16x8*)pb0;
    bf16x8 b1 = *(const bf16x8*)pb1;

    for (int k = 32; k < K; k += 32) {
        bf16x8 na0 = *(const bf16x8*)(pa0 + k);
        bf16x8 na1 = *(const bf16x8*)(pa1 + k);
        bf16x8 nb0 = *(const bf16x8*)(pb0 + k);
        bf16x8 nb1 = *(const bf16x8*)(pb1 + k);
        acc00 = __builtin_amdgcn_mfma_f32_16x16x32_bf16(a0, b0, acc00, 0, 0, 0);
        acc01 = __builtin_amdgcn_mfma_f32_16x16x32_bf16(a0, b1, acc01, 0, 0, 0);
        acc10 = __builtin_amdgcn_mfma_f32_16x16x32_bf16(a1, b0, acc10, 0, 0, 0);
        acc11 = __builtin_amdgcn_mfma_f32_16x16x32_bf16(a1, b1, acc11, 0, 0, 0);
        a0 = na0; a1 = na1; b0 = nb0; b1 = nb1;
    }
    acc00 = __builtin_amdgcn_mfma_f32_16x16x32_bf16(a0, b0, acc00, 0, 0, 0);
    acc01 = __builtin_amdgcn_mfma_f32_16x16x32_bf16(a0, b1, acc01, 0, 0, 0);
    acc10 = __builtin_amdgcn_mfma_f32_16x16x32_bf16(a1, b0, acc10, 0, 0, 0);
    acc11 = __builtin_amdgcn_mfma_f32_16x16x32_bf16(a1, b1, acc11, 0, 0, 0);

    const float bias0 = bias[n0 + r];
    const float bias1 = bias[n0 + 16 + r];
    #pragma unroll
    for (int i = 0; i < 4; ++i) {
        const int row0 = m0 + (q << 2) + i;      // acc0x rows
        const int row1 = row0 + 16;              // acc1x rows
        float v00 = fmaxf(acc00[i] + bias0, 0.f);
        float v01 = fmaxf(acc01[i] + bias1, 0.f);
        float v10 = fmaxf(acc10[i] + bias0, 0.f);
        float v11 = fmaxf(acc11[i] + bias1, 0.f);
        if (LAST) {
            // out[b, n, j]: m = b*64 + j ; stride (16384, 64, 1)
            float* O = (float*)Yv;
            const int b0r = row0 >> 6, j0 = row0 & 63;
            const int b1r = row1 >> 6, j1 = row1 & 63;
            O[(size_t)b0r * 16384 + (size_t)(n0 + r)      * 64 + j0] = v00;
            O[(size_t)b0r * 16384 + (size_t)(n0 + 16 + r) * 64 + j0] = v01;
            O[(size_t)b1r * 16384 + (size_t)(n0 + r)      * 64 + j1] = v10;
            O[(size_t)b1r * 16384 + (size_t)(n0 + 16 + r) * 64 + j1] = v11;
        } else {
            __hip_bfloat16* Y = (__hip_bfloat16*)Yv;
            Y[(size_t)row0 * N + n0 + r]      = __float2bfloat16(v00);
            Y[(size_t)row0 * N + n0 + 16 + r] = __float2bfloat16(v01);
            Y[(size_t)row1 * N + n0 + r]      = __float2bfloat16(v10);
            Y[(size_t)row1 * N + n0 + 16 + r] = __float2bfloat16(v11);
        }
    }
}

extern "C" void kernel_launch(void* const* d_in, const int* in_sizes, int n_in,
                              void* d_out, int out_size, void* d_ws, size_t ws_size,
                              hipStream_t stream) {
    (void)in_sizes; (void)n_in; (void)out_size; (void)ws_size;
    const float* heatmap   = (const float*)d_in[0];
    const float* pos_embed = (const float*)d_in[1];
    const float* feat1     = (const float*)d_in[2];
    const float* feat2     = (const float*)d_in[3];
    const float* feat3     = (const float*)d_in[4];
    const float* W1 = (const float*)d_in[5];  const float* b1 = (const float*)d_in[6];
    const float* W2 = (const float*)d_in[7];  const float* b2 = (const float*)d_in[8];
    const float* W3 = (const float*)d_in[9];  const float* b3 = (const float*)d_in[10];
    const float* W4 = (const float*)d_in[11]; const float* b4 = (const float*)d_in[12];
    float* out = (float*)d_out;

    char* ws = (char*)d_ws;
    int*   peaks = (int*)ws;                          // 1024 ints
    short* X0 = (short*)(ws + 8192);                  // 1024 x 992  bf16
    short* X1 = X0 + (size_t)1024 * 992;              // 1024 x 1024 bf16
    short* X2 = X1 + (size_t)1024 * 1024;             // 1024 x 512  bf16
    short* X3 = X2 + (size_t)1024 * 512;              // 1024 x 256  bf16
    short* T1 = X3 + (size_t)1024 * 256;              // 1024 x 992  bf16 (W1^T)
    short* T2 = T1 + (size_t)1024 * 992;              // 512  x 1024 bf16 (W2^T)
    short* T3 = T2 + (size_t)512 * 1024;              // 256  x 512  bf16 (W3^T)
    short* T4 = T3 + (size_t)256 * 512;               // 224  x 256  bf16 (W4^T)

    wcast_kernel<<<1688, 256, 0, stream>>>(W1, W2, W3, W4,
        (__hip_bfloat16*)T1, (__hip_bfloat16*)T2, (__hip_bfloat16*)T3, (__hip_bfloat16*)T4);
    argmax_kernel<<<1024, 256, 0, stream>>>(heatmap, peaks);
    gather_kernel<<<1024, 256, 0, stream>>>(pos_embed, feat1, feat2, feat3, peaks,
                                            (__hip_bfloat16*)X0, out);
    mfma_gemm<false><<<dim3(32, 32), 64, 0, stream>>>(X0, T1, b1, X1, 1024,  992);
    mfma_gemm<false><<<dim3(16, 32), 64, 0, stream>>>(X1, T2, b2, X2,  512, 1024);
    mfma_gemm<false><<<dim3( 8, 32), 64, 0, stream>>>(X2, T3, b3, X3,  256,  512);
    mfma_gemm<true ><<<dim3( 7, 32), 64, 0, stream>>>(X3, T4, b4, out, 224,  256);
}

// Round 3
// 596.030 us; speedup vs baseline: 1.2603x; 1.0140x over previous
//
#include <hip/hip_runtime.h>
#include <hip/hip_bf16.h>
#include <cstddef>
#include <cstdint>

// ---------------------------------------------------------------------------
//  heatmap  (16, 64, 256, 256)  f32
//  pos_embed(16, 32, 256, 256)  f32
//  feat1    (16, 96, 128, 128)  f32
//  feat2    (16,384,  64,  64)  f32
//  feat3    (16,512,  32,  32)  f32
//  W1 (992,1024) ; W2(1024,512) ; W3(512,256) ; W4(256,224)  + biases
//  out (16, 256, 64) f32 : ch 0..223 = MLP out (transposed), 224..255 = positions
//
//  Pipeline (2 structural phases):
//   K1: fused [argmax+gather] (blocks 0..1023, one per plane)
//       + [weight transpose/cast] (blocks 1024..2711)          -- one launch
//   K2-K5: MFMA bf16 GEMMs (wave-per-32x32-tile, LDS-free, reg prefetch)
//
//  NOTE (round-2 finding): ~480 us of dur_us is harness restore/poison
//  (1 GB ws fill @160 us etc.) inside the timed window — fixed overhead.
// ---------------------------------------------------------------------------

typedef __attribute__((ext_vector_type(8))) short bf16x8;   // 8 bf16 = 4 VGPRs
typedef __attribute__((ext_vector_type(4))) float f32x4;

// ---- bilinear gather helper ----------------------------------------------
__device__ inline void bilinear_block(const float* __restrict__ fb, int C, int H, int W,
                                      float gx, float gy,
                                      __hip_bfloat16* __restrict__ dst, int tid) {
    const float x = (gx + 1.0f) * 0.5f * (float)(W - 1);
    const float y = (gy + 1.0f) * 0.5f * (float)(H - 1);
    const float x0f = floorf(x), y0f = floorf(y);
    const float wx = x - x0f, wy = y - y0f;
    const int x0 = (int)fminf(fmaxf(x0f,       0.f), (float)(W - 1));
    const int x1 = (int)fminf(fmaxf(x0f + 1.f, 0.f), (float)(W - 1));
    const int y0 = (int)fminf(fmaxf(y0f,       0.f), (float)(H - 1));
    const int y1 = (int)fminf(fmaxf(y0f + 1.f, 0.f), (float)(H - 1));
    const float w00 = (1.f - wx) * (1.f - wy);
    const float w01 = wx * (1.f - wy);
    const float w10 = (1.f - wx) * wy;
    const float w11 = wx * wy;
    const int i00 = y0 * W + x0, i01 = y0 * W + x1;
    const int i10 = y1 * W + x0, i11 = y1 * W + x1;
    const size_t HW = (size_t)H * W;
    for (int c = tid; c < C; c += 256) {
        const float* fc = fb + (size_t)c * HW;
        float v = fc[i00] * w00 + fc[i01] * w01 + fc[i10] * w10 + fc[i11] * w11;
        dst[c] = __float2bfloat16(v);
    }
}

// ---- K1: fused argmax+gather (blocks 0..1023) + wcast (blocks 1024..2711) -
__global__ __launch_bounds__(256) void fused_front_kernel(
    const float* __restrict__ hm,
    const float* __restrict__ pos_embed,
    const float* __restrict__ feat1, const float* __restrict__ feat2,
    const float* __restrict__ feat3,
    const float* __restrict__ W1, const float* __restrict__ W2,
    const float* __restrict__ W3, const float* __restrict__ W4,
    __hip_bfloat16* __restrict__ T1, __hip_bfloat16* __restrict__ T2,
    __hip_bfloat16* __restrict__ T3, __hip_bfloat16* __restrict__ T4,
    __hip_bfloat16* __restrict__ X0, float* __restrict__ out) {
    __shared__ float smem[32 * 33];            // wcast tile; reused by argmax
    float* sval = smem;                        // [256]
    int*   sidx = (int*)(smem + 256);          // [256]
    const int tid = threadIdx.x;

    if (blockIdx.x >= 1024) {
        // ---------------- weight transpose + cast ----------------
        int bid = blockIdx.x - 1024;
        const float* W; __hip_bfloat16* T; int K, N;
        if (bid < 992)        { W = W1; T = T1; K = 992;  N = 1024; }
        else if (bid < 1504)  { bid -= 992;  W = W2; T = T2; K = 1024; N = 512; }
        else if (bid < 1632)  { bid -= 1504; W = W3; T = T3; K = 512;  N = 256; }
        else                  { bid -= 1632; W = W4; T = T4; K = 256;  N = 224; }
        const int tilesN = N >> 5;
        const int tk = bid / tilesN, tn = bid - tk * tilesN;
        float (*tile)[33] = (float(*)[33])smem;
        const int col = tid & 31, rowg = tid >> 5;   // rowg 0..7
        #pragma unroll
        for (int i = 0; i < 4; ++i) {
            int k = (tk << 5) + rowg + (i << 3);
            tile[rowg + (i << 3)][col] = W[(size_t)k * N + (tn << 5) + col];
        }
        __syncthreads();
        #pragma unroll
        for (int i = 0; i < 4; ++i) {
            int n = (tn << 5) + rowg + (i << 3);
            T[(size_t)n * K + (tk << 5) + col] = __float2bfloat16(tile[col][rowg + (i << 3)]);
        }
        return;
    }

    // ---------------- per-plane argmax ----------------
    const int plane = blockIdx.x;               // b*64 + j
    const float4* p4 = (const float4*)(hm + (size_t)plane * 65536);
    float best = -3.402823466e38f;
    int bidx = 0;
    for (int i = tid; i < 16384; i += 256) {
        float4 v = p4[i];
        int base = i << 2;
        if (v.x > best) { best = v.x; bidx = base; }
        if (v.y > best) { best = v.y; bidx = base + 1; }
        if (v.z > best) { best = v.z; bidx = base + 2; }
        if (v.w > best) { best = v.w; bidx = base + 3; }
    }
    sval[tid] = best; sidx[tid] = bidx;
    __syncthreads();
    for (int s = 128; s > 0; s >>= 1) {
        if (tid < s) {
            float ov = sval[tid + s]; int oi = sidx[tid + s];
            if (ov > sval[tid] || (ov == sval[tid] && oi < sidx[tid])) {
                sval[tid] = ov; sidx[tid] = oi;
            }
        }
        __syncthreads();
    }
    const int idx = sidx[0];

    // ---------------- gather (same block, no round-trip) ----------------
    const int b = plane >> 6, j = plane & 63;
    const int py = idx >> 8, px = idx & 255;
    const float gx = ((float)px - 127.5f) / 127.5f;
    const float gy = ((float)py - 127.5f) / 127.5f;

    if (tid < 32) {
        float v = pos_embed[((size_t)(b * 32 + tid)) * 65536 + idx];
        out[(size_t)b * 16384 + (size_t)(224 + tid) * 64 + j] = v;
    }

    __hip_bfloat16* xrow = X0 + (size_t)plane * 992;
    bilinear_block(feat1 + (size_t)b *  96 * 128 * 128,  96, 128, 128, gx, gy, xrow,       tid);
    bilinear_block(feat2 + (size_t)b * 384 *  64 *  64, 384,  64,  64, gx, gy, xrow +  96, tid);
    bilinear_block(feat3 + (size_t)b * 512 *  32 *  32, 512,  32,  32, gx, gy, xrow + 480, tid);
}

// ---- K2-K5: MFMA bf16 GEMM, one wave per 32x32 output tile ----------------
// A: [M][K] bf16 row-major. Bt: [N][K] bf16 (W transposed). Y=relu(A@W+b).
// A-frag: lane holds A[m0 + (lane&15)][ (lane>>4)*8 + j ] -> 16B contiguous.
// C/D: col = lane&15, row = (lane>>4)*4 + reg   [learn_hip m89/m91]
template<bool LAST>
__global__ __launch_bounds__(64) void mfma_gemm(
    const short* __restrict__ A, const short* __restrict__ Bt,
    const float* __restrict__ bias, void* __restrict__ Yv,
    int N, int K) {
    const int lane = threadIdx.x;
    const int q = lane >> 4, r = lane & 15;
    const int m0 = blockIdx.y << 5;
    const int n0 = blockIdx.x << 5;

    const short* pa0 = A  + (size_t)(m0 + r) * K + (q << 3);
    const short* pa1 = pa0 + (size_t)16 * K;
    const short* pb0 = Bt + (size_t)(n0 + r) * K + (q << 3);
    const short* pb1 = pb0 + (size_t)16 * K;

    f32x4 acc00 = {0.f,0.f,0.f,0.f}, acc01 = {0.f,0.f,0.f,0.f};
    f32x4 acc10 = {0.f,0.f,0.f,0.f}, acc11 = {0.f,0.f,0.f,0.f};

    bf16x8 a0 = *(const bf16x8*)pa0;
    bf16x8 a1 = *(const bf16x8*)pa1;
    bf16x8 b0 = *(const bf16x8*)pb0;
    bf16x8 b1 = *(const bf16x8*)pb1;

    for (int k = 32; k < K; k += 32) {
        bf16x8 na0 = *(const bf16x8*)(pa0 + k);
        bf16x8 na1 = *(const bf16x8*)(pa1 + k);
        bf16x8 nb0 = *(const bf16x8*)(pb0 + k);
        bf16x8 nb1 = *(const bf16x8*)(pb1 + k);
        acc00 = __builtin_amdgcn_mfma_f32_16x16x32_bf16(a0, b0, acc00, 0, 0, 0);
        acc01 = __builtin_amdgcn_mfma_f32_16x16x32_bf16(a0, b1, acc01, 0, 0, 0);
        acc10 = __builtin_amdgcn_mfma_f32_16x16x32_bf16(a1, b0, acc10, 0, 0, 0);
        acc11 = __builtin_amdgcn_mfma_f32_16x16x32_bf16(a1, b1, acc11, 0, 0, 0);
        a0 = na0; a1 = na1; b0 = nb0; b1 = nb1;
    }
    acc00 = __builtin_amdgcn_mfma_f32_16x16x32_bf16(a0, b0, acc00, 0, 0, 0);
    acc01 = __builtin_amdgcn_mfma_f32_16x16x32_bf16(a0, b1, acc01, 0, 0, 0);
    acc10 = __builtin_amdgcn_mfma_f32_16x16x32_bf16(a1, b0, acc10, 0, 0, 0);
    acc11 = __builtin_amdgcn_mfma_f32_16x16x32_bf16(a1, b1, acc11, 0, 0, 0);

    const float bias0 = bias[n0 + r];
    const float bias1 = bias[n0 + 16 + r];
    #pragma unroll
    for (int i = 0; i < 4; ++i) {
        const int row0 = m0 + (q << 2) + i;      // acc0x rows
        const int row1 = row0 + 16;              // acc1x rows
        float v00 = fmaxf(acc00[i] + bias0, 0.f);
        float v01 = fmaxf(acc01[i] + bias1, 0.f);
        float v10 = fmaxf(acc10[i] + bias0, 0.f);
        float v11 = fmaxf(acc11[i] + bias1, 0.f);
        if (LAST) {
            // out[b, n, j]: m = b*64 + j ; stride (16384, 64, 1)
            float* O = (float*)Yv;
            const int b0r = row0 >> 6, j0 = row0 & 63;
            const int b1r = row1 >> 6, j1 = row1 & 63;
            O[(size_t)b0r * 16384 + (size_t)(n0 + r)      * 64 + j0] = v00;
            O[(size_t)b0r * 16384 + (size_t)(n0 + 16 + r) * 64 + j0] = v01;
            O[(size_t)b1r * 16384 + (size_t)(n0 + r)      * 64 + j1] = v10;
            O[(size_t)b1r * 16384 + (size_t)(n0 + 16 + r) * 64 + j1] = v11;
        } else {
            __hip_bfloat16* Y = (__hip_bfloat16*)Yv;
            Y[(size_t)row0 * N + n0 + r]      = __float2bfloat16(v00);
            Y[(size_t)row0 * N + n0 + 16 + r] = __float2bfloat16(v01);
            Y[(size_t)row1 * N + n0 + r]      = __float2bfloat16(v10);
            Y[(size_t)row1 * N + n0 + 16 + r] = __float2bfloat16(v11);
        }
    }
}

extern "C" void kernel_launch(void* const* d_in, const int* in_sizes, int n_in,
                              void* d_out, int out_size, void* d_ws, size_t ws_size,
                              hipStream_t stream) {
    (void)in_sizes; (void)n_in; (void)out_size; (void)ws_size;
    const float* heatmap   = (const float*)d_in[0];
    const float* pos_embed = (const float*)d_in[1];
    const float* feat1     = (const float*)d_in[2];
    const float* feat2     = (const float*)d_in[3];
    const float* feat3     = (const float*)d_in[4];
    const float* W1 = (const float*)d_in[5];  const float* b1 = (const float*)d_in[6];
    const float* W2 = (const float*)d_in[7];  const float* b2 = (const float*)d_in[8];
    const float* W3 = (const float*)d_in[9];  const float* b3 = (const float*)d_in[10];
    const float* W4 = (const float*)d_in[11]; const float* b4 = (const float*)d_in[12];
    float* out = (float*)d_out;

    char* ws = (char*)d_ws;
    short* X0 = (short*)(ws + 8192);                  // 1024 x 992  bf16
    short* X1 = X0 + (size_t)1024 * 992;              // 1024 x 1024 bf16
    short* X2 = X1 + (size_t)1024 * 1024;             // 1024 x 512  bf16
    short* X3 = X2 + (size_t)1024 * 512;              // 1024 x 256  bf16
    short* T1 = X3 + (size_t)1024 * 256;              // 1024 x 992  bf16 (W1^T)
    short* T2 = T1 + (size_t)1024 * 992;              // 512  x 1024 bf16 (W2^T)
    short* T3 = T2 + (size_t)512 * 1024;              // 256  x 512  bf16 (W3^T)
    short* T4 = T3 + (size_t)256 * 512;               // 224  x 256  bf16 (W4^T)

    fused_front_kernel<<<2712, 256, 0, stream>>>(
        heatmap, pos_embed, feat1, feat2, feat3,
        W1, W2, W3, W4,
        (__hip_bfloat16*)T1, (__hip_bfloat16*)T2, (__hip_bfloat16*)T3, (__hip_bfloat16*)T4,
        (__hip_bfloat16*)X0, out);
    mfma_gemm<false><<<dim3(32, 32), 64, 0, stream>>>(X0, T1, b1, X1, 1024,  992);
    mfma_gemm<false><<<dim3(16, 32), 64, 0, stream>>>(X1, T2, b2, X2,  512, 1024);
    mfma_gemm<false><<<dim3( 8, 32), 64, 0, stream>>>(X2, T3, b3, X3,  256,  512);
    mfma_gemm<true ><<<dim3( 7, 32), 64, 0, stream>>>(X3, T4, b4, out, 224,  256);
}